// Round 6
// baseline (360.511 us; speedup 1.0000x reference)
//
#include <hip/hip_runtime.h>

// ---------------------------------------------------------------------------
// AttentionBlock (RMSNorm -> gated windowed attention -> RMSNorm -> SwiGLU FFN)
// MI355X / gfx950.  R6: per-CU staging-BW model (20 B/cyc) says 128^2 tiles
// cap at ~31% MfmaUtil -> wo (N=1024,K=4096) moved to 256^2 split-K=4 with
// bf16 partials in dead ws + fused reduce. CFG0 gains m201-style read-hoist
// (P1/P3 frags issued in P0/P2 regions; ledger-verified safe).
// ---------------------------------------------------------------------------

#define DEV __device__ __forceinline__

using u16 = unsigned short;
typedef __attribute__((ext_vector_type(8))) short  short8;   // 8 x bf16
typedef __attribute__((ext_vector_type(4))) float  floatx4;

DEV u16 f2bf(float f) {
  unsigned u = __builtin_bit_cast(unsigned, f);
  u += 0x7FFFu + ((u >> 16) & 1u);
  return (u16)(u >> 16);
}
DEV float bf2f(u16 h) {
  unsigned u = ((unsigned)h) << 16;
  return __builtin_bit_cast(float, u);
}
DEV floatx4 mfma16(short8 a, short8 b, floatx4 c) {
  return __builtin_amdgcn_mfma_f32_16x16x32_bf16(a, b, c, 0, 0, 0);
}
DEV void gload16(const u16* g, const char* lds_base_wave_uniform) {
  __builtin_amdgcn_global_load_lds(
      (const __attribute__((address_space(1))) void*)g,
      (__attribute__((address_space(3))) void*)lds_base_wave_uniform,
      16, 0, 0);
}
#define WAITVM(n) asm volatile("s_waitcnt vmcnt(" #n ")" ::: "memory")
DEV void blockbar() {
  asm volatile("" ::: "memory");
  __builtin_amdgcn_s_barrier();
  asm volatile("" ::: "memory");
}

// ---------------------------------------------------------------------------
// Fused fp32 -> bf16 weight conversion (one launch, 17408 blocks)
// ---------------------------------------------------------------------------
__global__ __launch_bounds__(256) void cvt_all_k(
    const float* __restrict__ s0, const float* __restrict__ s1,
    const float* __restrict__ s2, const float* __restrict__ s3,
    const float* __restrict__ s4, const float* __restrict__ s5,
    u16* __restrict__ d0, u16* __restrict__ d1, u16* __restrict__ d2,
    u16* __restrict__ d3, u16* __restrict__ d4, u16* __restrict__ d5) {
  const int b = blockIdx.x;
  const float* in; u16* out; int base;
  if (b < 3072)       { in = s0; out = d0; base = 0; }
  else if (b < 4096)  { in = s1; out = d1; base = 3072; }
  else if (b < 5120)  { in = s2; out = d2; base = 4096; }
  else if (b < 9216)  { in = s3; out = d3; base = 5120; }
  else if (b < 13312) { in = s4; out = d4; base = 9216; }
  else                { in = s5; out = d5; base = 13312; }
  const size_t i = (size_t)(b - base) * 256 + threadIdx.x;
  const float4 v = ((const float4*)in)[i];
  ushort4 r;
  r.x = f2bf(v.x); r.y = f2bf(v.y); r.z = f2bf(v.z); r.w = f2bf(v.w);
  ((ushort4*)out)[i] = r;
}

// ---------------------------------------------------------------------------
// RMSNorm: one block per row (1024 cols), fp32 in -> bf16 out
// ---------------------------------------------------------------------------
__global__ __launch_bounds__(256) void rmsnorm_k(const float* __restrict__ x,
                                                 const float* __restrict__ wt,
                                                 u16* __restrict__ o) {
  __shared__ float red[4];
  const int row = blockIdx.x;
  const int tid = threadIdx.x;
  const float4 v = ((const float4*)(x + (size_t)row * 1024))[tid];
  float ss = v.x * v.x + v.y * v.y + v.z * v.z + v.w * v.w;
  ss += __shfl_xor(ss, 1, 64);
  ss += __shfl_xor(ss, 2, 64);
  ss += __shfl_xor(ss, 4, 64);
  ss += __shfl_xor(ss, 8, 64);
  ss += __shfl_xor(ss, 16, 64);
  ss += __shfl_xor(ss, 32, 64);
  if ((tid & 63) == 0) red[tid >> 6] = ss;
  __syncthreads();
  const float tot = red[0] + red[1] + red[2] + red[3];
  const float sc = rsqrtf(tot * (1.0f / 1024.0f) + 1e-6f);
  const float4 wv = ((const float4*)wt)[tid];
  ushort4 r;
  r.x = f2bf(v.x * sc * wv.x);
  r.y = f2bf(v.y * sc * wv.y);
  r.z = f2bf(v.z * sc * wv.z);
  r.w = f2bf(v.w * sc * wv.w);
  ((ushort4*)(o + (size_t)row * 1024))[tid] = r;
}

// ---------------------------------------------------------------------------
// split-K reduce: out[i] = x2[i] + sum_s bf16(part[s][i]), 4 floats/thread
// ---------------------------------------------------------------------------
__global__ __launch_bounds__(256) void reduce4_k(const u16* __restrict__ part,
                                                 const float* __restrict__ x2,
                                                 float* __restrict__ out) {
  const size_t i = ((size_t)blockIdx.x * 256 + threadIdx.x) * 4;
  float4 r = *(const float4*)(x2 + i);
#pragma unroll
  for (int s = 0; s < 4; s++) {
    const ushort4 pv = *(const ushort4*)(part + (size_t)s * 4194304 + i);
    r.x += bf2f(pv.x); r.y += bf2f(pv.y); r.z += bf2f(pv.z); r.w += bf2f(pv.w);
  }
  *(float4*)(out + i) = r;
}

// ---------------------------------------------------------------------------
// 8-phase pipelined GEMM: C[M,N] = A[M,Kall] @ B[N,Kall]^T over K-range
// [blockIdx.z*ksz, +ksz).  Both CFGs: 512 thr, 8 waves as 2(M) x 4(N).
// CFG0: 256x256 tile, 4 phases/tile, LDS 128 KiB; P1/P3 frag reads hoisted
//       into P0/P2 regions (their groups are awaited at P0/P2's vmcnt+bar).
// CFG1: 128x128 tile, 2 phases/tile, LDS 64 KiB (no hoist possible: ks1
//       groups not yet awaited at E0).
// BK=64. Groups [A_ks0 | A_ks1 | B_ks0 | B_ks1], each [BM][64B].
// LDS slot swizzle: byte = row*64 + ((g ^ ((row>>1)&3))<<4); inverse applied
// to the global SOURCE k-group (kg_src = (lane&3)^((lane>>3)&3)); gload dest
// linear (rule #21).  Stage ledger per tile t (for t+1): A0@P0, B0@P1,
// A1@P2, B1@P3; waits vmcnt(4) at P0 (need A0,B0) and P2 (need A1,B1).
// Epilogues: 2 silu | 3 v*aux | 4 v+resid fp32 | 6 qkv/gate split |
//            7 bf16 partial at cb + z*4M (split-K)
// ---------------------------------------------------------------------------
template <int CFG, int EPI>
__global__ __launch_bounds__(512, 2) void gemm8p(
    const u16* __restrict__ Ag, const u16* __restrict__ Bg, int N, int K,
    int ksz, u16* __restrict__ cb, float* __restrict__ cf,
    const u16* __restrict__ aux, const float* __restrict__ resid,
    u16* __restrict__ cb2) {
  constexpr int BM = (CFG == 0) ? 256 : 128;
  constexpr int WM = (CFG == 0) ? 128 : 64;
  constexpr int WN = (CFG == 0) ? 64 : 32;
  constexpr int NI = WM / 16;                  // 8 / 4
  constexpr int NJ = WN / 16;                  // 4 / 2
  constexpr int IH = (CFG == 0) ? NI / 2 : NI; // frags per mm (4 / 4)
  constexpr int GB = BM * 64;                  // group bytes: 16K / 8K
  constexpr int QI = (CFG == 0) ? 2 : 1;       // gloads per lane per group
  constexpr int BUFB = 4 * GB;
  __shared__ __align__(16) char lds[2 * BUFB];

  const int tid = threadIdx.x;
  const int w = tid >> 6, lane = tid & 63;
  const int wm = w >> 2, wn = w & 3;
  const int g = lane >> 4, r16 = lane & 15;
  const int gx = (g ^ ((r16 >> 1) & 3)) << 4;  // swizzled 16B slot offset

  // T1 XCD swizzle (grid.x*grid.y % 8 == 0 for all launches here)
  int bid = blockIdx.y * gridDim.x + blockIdx.x;
  const int cpx = (gridDim.x * gridDim.y) >> 3;
  bid = (bid & 7) * cpx + (bid >> 3);
  const int m0 = (bid / gridDim.x) * BM;
  const int n0 = (bid % gridDim.x) * BM;
  const int kbeg = blockIdx.z * ksz;

  floatx4 acc[NI][NJ];
#pragma unroll
  for (int i = 0; i < NI; i++)
#pragma unroll
    for (int j = 0; j < NJ; j++) acc[i][j] = (floatx4){0.f, 0.f, 0.f, 0.f};

  const int nt = ksz >> 6;

  // stage one group G (0:A_ks0 1:A_ks1 2:B_ks0 3:B_ks1) of tile t
  const int kg_src = (lane & 3) ^ ((lane >> 3) & 3);  // inverse swizzle
  auto stageG = [&](int G, int t) {
    if (t >= nt) return;
    const u16* Mat = (G < 2) ? Ag : Bg;
    const int b0 = (G < 2) ? m0 : n0;
    const int kc = kbeg + t * 64 + (G & 1) * 32 + kg_src * 8;
    const char* dst = lds + (t & 1) * BUFB + G * GB + w * 1024;
#pragma unroll
    for (int q = 0; q < QI; q++) {
      const int row = q * 128 + w * 16 + (lane >> 2);
      gload16(Mat + (size_t)(b0 + row) * K + kc, dst + q * 8192);
    }
  };

  auto rdA = [&](short8* af, int ks, int ihalf, const char* buf) {
#pragma unroll
    for (int i = 0; i < IH; i++) {
      const int arow = wm * WM + (ihalf * IH + i) * 16 + r16;
      af[i] = *(const short8*)(buf + ks * GB + arow * 64 + gx);
    }
  };
  auto rdB = [&](short8* bf_, int ks, const char* buf) {
#pragma unroll
    for (int j = 0; j < NJ; j++) {
      const int brow = wn * WN + j * 16 + r16;
      bf_[j] = *(const short8*)(buf + 2 * GB + ks * GB + brow * 64 + gx);
    }
  };
  auto mm = [&](short8* af, short8* bf_, int ihalf) {
    __builtin_amdgcn_s_setprio(1);
#pragma unroll
    for (int i = 0; i < IH; i++)
#pragma unroll
      for (int j = 0; j < NJ; j++)
        acc[ihalf * IH + i][j] = mfma16(af[i], bf_[j], acc[ihalf * IH + i][j]);
    __builtin_amdgcn_s_setprio(0);
  };

  // prologue: tile 0 in ledger order A0, B0, A1, B1
  stageG(0, 0); stageG(2, 0); stageG(1, 0); stageG(3, 0);

  for (int t = 0; t < nt; ++t) {
    const char* buf = lds + (t & 1) * BUFB;
    if constexpr (CFG == 0) {
      short8 af0[IH], af1[IH], bfv[NJ];
      // P0: ks0 ih0 (+ hoisted P1 reads: same awaited A0 group)
      WAITVM(4);
      blockbar();
      rdA(af0, 0, 0, buf); rdB(bfv, 0, buf);
      stageG(0, t + 1);
      rdA(af1, 0, 1, buf);
      mm(af0, bfv, 0);
      // P1: ks0 ih1 (frags already in regs)
      blockbar();
      stageG(2, t + 1);
      mm(af1, bfv, 1);
      // P2: ks1 ih0 (+ hoisted P3 reads: same awaited A1 group)
      if (t + 1 < nt) { WAITVM(4); } else { WAITVM(0); }
      blockbar();
      rdA(af0, 1, 0, buf); rdB(bfv, 1, buf);
      stageG(1, t + 1);
      rdA(af1, 1, 1, buf);
      mm(af0, bfv, 0);
      // P3: ks1 ih1
      blockbar();
      stageG(3, t + 1);
      mm(af1, bfv, 1);
    } else {
      short8 af[IH], bfv[NJ];
      // E0: ks0, all i
      WAITVM(2);
      blockbar();
      rdA(af, 0, 0, buf); rdB(bfv, 0, buf);
      stageG(0, t + 1); stageG(2, t + 1);
      mm(af, bfv, 0);
      // E1: ks1, all i
      if (t + 1 < nt) { WAITVM(2); } else { WAITVM(0); }
      blockbar();
      rdA(af, 1, 0, buf); rdB(bfv, 1, buf);
      stageG(1, t + 1); stageG(3, t + 1);
      mm(af, bfv, 0);
    }
  }

  // epilogue
#pragma unroll
  for (int i = 0; i < NI; i++) {
    const int row = m0 + wm * WM + i * 16 + g * 4;
#pragma unroll
    for (int j = 0; j < NJ; j++) {
      const int col = n0 + wn * WN + j * 16 + r16;
#pragma unroll
      for (int rr = 0; rr < 4; rr++) {
        const float v = acc[i][j][rr];
        if constexpr (EPI == 2) {
          cb[(size_t)(row + rr) * N + col] = f2bf(v / (1.0f + __expf(-v)));
        } else if constexpr (EPI == 3) {
          const size_t idx = (size_t)(row + rr) * N + col;
          cb[idx] = f2bf(v * bf2f(aux[idx]));
        } else if constexpr (EPI == 4) {
          const size_t idx = (size_t)(row + rr) * N + col;
          cf[idx] = v + resid[idx];
        } else if constexpr (EPI == 6) {
          if (col < 3072)
            cb[(size_t)(row + rr) * 3072 + col] = f2bf(v);
          else
            cb2[(size_t)(row + rr) * 1024 + (col - 3072)] =
                f2bf(1.0f / (1.0f + __expf(-v)));
        } else if constexpr (EPI == 7) {
          (cb + (size_t)blockIdx.z * 4194304)[(size_t)(row + rr) * N + col] =
              f2bf(v);
        }
      }
    }
  }
}

// ---------------------------------------------------------------------------
// Sliding-window causal attention (WINDOW=256) + fused sigmoid-gate multiply.
// (unchanged — validated R1-R5)
// ---------------------------------------------------------------------------
__global__ __launch_bounds__(256) void attn_win_kernel(
    const u16* __restrict__ qkv, const u16* __restrict__ gate,
    u16* __restrict__ out) {
  __shared__ __align__(16) u16 Kl[64][80];
  __shared__ __align__(16) u16 Vt[64][80];
  __shared__ __align__(16) u16 Pl[4][16][80];

  const int tid = threadIdx.x;
  const int w = tid >> 6, lane = tid & 63;
  const int g = lane >> 4, r16 = lane & 15;

  const int q0 = blockIdx.x * 64;
  const int h = blockIdx.y;
  const int b = blockIdx.z;
  const u16* qb_ = qkv + (size_t)b * 2048 * 3072;

  const int tq = q0 + w * 16 + r16;
  const u16* qptr = qb_ + (size_t)tq * 3072 + h * 64;
  const short8 aq0 = *(const short8*)(qptr + g * 8);
  const short8 aq1 = *(const short8*)(qptr + 32 + g * 8);

  floatx4 O[4] = {{0,0,0,0},{0,0,0,0},{0,0,0,0},{0,0,0,0}};
  float mrow[4] = {-1e30f, -1e30f, -1e30f, -1e30f};
  float lrow[4] = {0.f, 0.f, 0.f, 0.f};

  const int srow = tid >> 2;
  const int sq4 = tid & 3;
  const int qw = q0 + w * 16;

  for (int kt = q0 - 256; kt <= q0; kt += 64) {
    if (kt < 0) continue;
    {
      const u16* kb = qb_ + (size_t)(kt + srow) * 3072 + 1024 + h * 64 + sq4 * 16;
      const short8 kv0 = *(const short8*)kb;
      const short8 kv1 = *(const short8*)(kb + 8);
      *(short8*)&Kl[srow][sq4 * 16] = kv0;
      *(short8*)&Kl[srow][sq4 * 16 + 8] = kv1;
      const u16* vb = kb + 1024;
      const short8 vv0 = *(const short8*)vb;
      const short8 vv1 = *(const short8*)(vb + 8);
#pragma unroll
      for (int j = 0; j < 8; j++) Vt[sq4 * 16 + j][srow] = (u16)vv0[j];
#pragma unroll
      for (int j = 0; j < 8; j++) Vt[sq4 * 16 + 8 + j][srow] = (u16)vv1[j];
    }
    __syncthreads();

    const bool active = (qw + 15 >= kt) && (qw - kt < 319);
    if (active) {
      floatx4 S[4];
#pragma unroll
      for (int nf = 0; nf < 4; nf++) {
        const short8 bk0 = *(const short8*)&Kl[nf * 16 + r16][g * 8];
        const short8 bk1 = *(const short8*)&Kl[nf * 16 + r16][32 + g * 8];
        floatx4 a = {0.f, 0.f, 0.f, 0.f};
        a = mfma16(aq0, bk0, a);
        a = mfma16(aq1, bk1, a);
        S[nf] = a;
      }
      float pm[4][4];
      float nmax[4] = {-1e30f, -1e30f, -1e30f, -1e30f};
#pragma unroll
      for (int nf = 0; nf < 4; nf++) {
        const int key = kt + nf * 16 + r16;
#pragma unroll
        for (int rr = 0; rr < 4; rr++) {
          const int q = qw + g * 4 + rr;
          const int dist = q - key;
          const float s = (dist >= 0 && dist < 256) ? S[nf][rr] : -1e30f;
          pm[nf][rr] = s;
          nmax[rr] = fmaxf(nmax[rr], s);
        }
      }
#pragma unroll
      for (int rr = 0; rr < 4; rr++) {
        float v = nmax[rr];
        v = fmaxf(v, __shfl_xor(v, 1, 64));
        v = fmaxf(v, __shfl_xor(v, 2, 64));
        v = fmaxf(v, __shfl_xor(v, 4, 64));
        v = fmaxf(v, __shfl_xor(v, 8, 64));
        const float mnew = fmaxf(mrow[rr], v);
        const float alpha = __expf(0.125f * (mrow[rr] - mnew));
        mrow[rr] = mnew;
        lrow[rr] *= alpha;
#pragma unroll
        for (int n = 0; n < 4; n++) O[n][rr] *= alpha;
        float ls = 0.f;
#pragma unroll
        for (int nf = 0; nf < 4; nf++) {
          const float s = pm[nf][rr];
          const float pv = (s < -1e29f) ? 0.f : __expf(0.125f * (s - mnew));
          pm[nf][rr] = pv;
          ls += pv;
        }
        ls += __shfl_xor(ls, 1, 64);
        ls += __shfl_xor(ls, 2, 64);
        ls += __shfl_xor(ls, 4, 64);
        ls += __shfl_xor(ls, 8, 64);
        lrow[rr] += ls;
      }
#pragma unroll
      for (int nf = 0; nf < 4; nf++)
#pragma unroll
        for (int rr = 0; rr < 4; rr++)
          Pl[w][g * 4 + rr][nf * 16 + r16] = f2bf(pm[nf][rr]);
#pragma unroll
      for (int kf = 0; kf < 2; kf++) {
        const short8 pa = *(const short8*)&Pl[w][r16][kf * 32 + g * 8];
#pragma unroll
        for (int n = 0; n < 4; n++) {
          const short8 vb8 = *(const short8*)&Vt[n * 16 + r16][kf * 32 + g * 8];
          O[n] = mfma16(pa, vb8, O[n]);
        }
      }
    }
    __syncthreads();
  }

#pragma unroll
  for (int n = 0; n < 4; n++) {
#pragma unroll
    for (int rr = 0; rr < 4; rr++) {
      const int t = qw + g * 4 + rr;
      const size_t idx = ((size_t)(b * 2048 + t)) * 1024 + h * 64 + n * 16 + r16;
      const float gv = bf2f(gate[idx]);
      const float ov = (O[n][rr] / lrow[rr]) * gv;
      out[idx] = f2bf(ov);
    }
  }
}

// ---------------------------------------------------------------------------
// Orchestration.  wo split-K partials overlay dead ws (xn..qkvb, 32 MB).
// ---------------------------------------------------------------------------
extern "C" void kernel_launch(void* const* d_in, const int* in_sizes, int n_in,
                              void* d_out, int out_size, void* d_ws,
                              size_t ws_size, hipStream_t stream) {
  (void)in_sizes; (void)n_in; (void)out_size; (void)ws_size;
  const float* x     = (const float*)d_in[0];
  const float* ln1   = (const float*)d_in[1];
  const float* qkvw  = (const float*)d_in[2];
  const float* gatew = (const float*)d_in[3];
  const float* outw  = (const float*)d_in[4];
  const float* ln2   = (const float*)d_in[5];
  const float* wg    = (const float*)d_in[6];
  const float* wu    = (const float*)d_in[7];
  const float* wo    = (const float*)d_in[8];
  float* outp = (float*)d_out;

  u16* p = (u16*)d_ws;
  u16* qkvw_b  = p; p += 3 * 1024 * 1024;   // adjacent to gatew_b (merged B)
  u16* gatew_b = p; p += 1024 * 1024;
  u16* outw_b  = p; p += 1024 * 1024;
  u16* wg_b    = p; p += 4 * 1024 * 1024;
  u16* wu_b    = p; p += 4 * 1024 * 1024;
  u16* wo_b    = p; p += 4 * 1024 * 1024;
  u16* xn      = p; p += 4096 * 1024;       // } dead by wo-time: reused as
  u16* qkvb    = p; p += (size_t)4096 * 3072; // } split-K partials (16M u16)
  u16* gates   = p; p += 4096 * 1024;
  u16* a3      = p; p += 4096 * 1024;
  u16* hb      = p; p += 4096 * 1024;
  u16* gs      = p; p += (size_t)4096 * 4096;
  float* x2    = (float*)p;
  u16* parts   = xn;                        // 4 x 4M u16 bf16 partials

  cvt_all_k<<<17408, 256, 0, stream>>>(qkvw, gatew, outw, wg, wu, wo,
                                       qkvw_b, gatew_b, outw_b, wg_b, wu_b, wo_b);

  rmsnorm_k<<<4096, 256, 0, stream>>>(x, ln1, xn);

  // merged qkv+gate: M=4096 N=4096 K=1024, 256^2 tiles, grid 16x16
  gemm8p<0, 6><<<dim3(16, 16), 512, 0, stream>>>(
      xn, qkvw_b, 4096, 1024, 1024, qkvb, nullptr, nullptr, nullptr, gates);

  attn_win_kernel<<<dim3(32, 16, 2), 256, 0, stream>>>(qkvb, gates, a3);

  // x2 = x + a3 @ out_w.T : M=4096 N=1024 K=1024, 128^2 tiles, grid 8x32
  gemm8p<1, 4><<<dim3(8, 32), 512, 0, stream>>>(
      a3, outw_b, 1024, 1024, 1024, nullptr, x2, nullptr, x, nullptr);

  rmsnorm_k<<<4096, 256, 0, stream>>>(x2, ln2, hb);

  // gs = silu(h @ wg.T); gs *= (h @ wu.T)
  gemm8p<0, 2><<<dim3(16, 16), 512, 0, stream>>>(
      hb, wg_b, 4096, 1024, 1024, gs, nullptr, nullptr, nullptr, nullptr);
  gemm8p<0, 3><<<dim3(16, 16), 512, 0, stream>>>(
      hb, wu_b, 4096, 1024, 1024, gs, nullptr, gs, nullptr, nullptr);

  // wo: M=4096 N=1024 K=4096 -> 256^2 tile split-K=4 (grid 4x16x4, AI=128),
  // bf16 partials into dead ws, then out = x2 + sum(partials)
  gemm8p<0, 7><<<dim3(4, 16, 4), 512, 0, stream>>>(
      gs, wo_b, 1024, 4096, 1024, parts, nullptr, nullptr, nullptr, nullptr);
  reduce4_k<<<4096, 256, 0, stream>>>(parts, x2, outp);
}